// Round 2
// baseline (618.760 us; speedup 1.0000x reference)
//
#include <hip/hip_runtime.h>
#include <math.h>

typedef unsigned short bfu;

__device__ __forceinline__ float b2f(bfu u) {
    unsigned int x = ((unsigned int)u) << 16;
    return __uint_as_float(x);
}
__device__ __forceinline__ bfu f2bf(float f) {
    unsigned int u = __float_as_uint(f);
    unsigned int r = (u + 0x7FFFu + ((u >> 16) & 1u)) >> 16;
    return (bfu)r;
}

// ---------------------------------------------------------------------------
// fused zero: deg[N], cdeg[NC], sumsq[512]
// ---------------------------------------------------------------------------
__global__ void k_zero3(int* __restrict__ deg, int N, int* __restrict__ cdeg, int NC,
                        float* __restrict__ sumsq) {
    int i = blockIdx.x * blockDim.x + threadIdx.x;
    if (i < N) deg[i] = 0;
    if (i < NC) cdeg[i] = 0;
    if (i < 512) sumsq[i] = 0.f;
}

// ---------------------------------------------------------------------------
// CSR build: histogram -> single-block scan -> scatter
// ---------------------------------------------------------------------------
__global__ void k_hist(const int* __restrict__ keys, int n, int* __restrict__ deg) {
    int i = blockIdx.x * blockDim.x + threadIdx.x;
    if (i < n) atomicAdd(&deg[keys[i]], 1);
}

__global__ void k_scan(const int* __restrict__ deg, int n,
                       int* __restrict__ ptr, int* __restrict__ cur) {
    __shared__ int part[1024];
    const int t = threadIdx.x;
    const int chunk = (n + 1023) / 1024;
    int b = t * chunk;
    int e = b + chunk; if (e > n) e = n;
    int s = 0;
    for (int i = b; i < e; i++) s += deg[i];
    part[t] = s;
    __syncthreads();
    for (int off = 1; off < 1024; off <<= 1) {
        int v = part[t];
        int u = (t >= off) ? part[t - off] : 0;
        __syncthreads();
        part[t] = v + u;
        __syncthreads();
    }
    int excl = (t == 0) ? 0 : part[t - 1];
    for (int i = b; i < e; i++) {
        ptr[i] = excl; cur[i] = excl;
        excl += deg[i];
    }
    if (t == 1023) ptr[n] = part[1023];
}

__global__ void k_scatter_edges(const int* __restrict__ dst, const int* __restrict__ src,
                                int E, int* __restrict__ cur, int* __restrict__ colidx) {
    int e = blockIdx.x * blockDim.x + threadIdx.x;
    if (e < E) {
        int d = dst[e];
        int pos = atomicAdd(&cur[d], 1);
        colidx[pos] = src[e];
    }
}

__global__ void k_scatter_nodes(const int* __restrict__ key, int N,
                                int* __restrict__ cur, int* __restrict__ idx) {
    int i = blockIdx.x * blockDim.x + threadIdx.x;
    if (i < N) {
        int c = key[i];
        int pos = atomicAdd(&cur[c], 1);
        idx[pos] = i;
    }
}

// ---------------------------------------------------------------------------
// GEMM 1: t = relu(x @ w1 + b1)   x:[M,K] (dense, stride K), w1:[K,64], t:[M,64]
// ---------------------------------------------------------------------------
template <int K>
__global__ __launch_bounds__(256) void k_mlp1(const float* __restrict__ x,
                                              const float* __restrict__ w1,
                                              const float* __restrict__ b1,
                                              float* __restrict__ t, int M) {
    __shared__ float xs[64][68];
    __shared__ float ws[64][68];
    const int tid = threadIdx.x;
    const int m0 = blockIdx.x * 64;
    const int rl = tid >> 4;
    const int c4 = (tid & 15) * 4;
    float acc[4][4] = {};

    for (int k0 = 0; k0 < K; k0 += 64) {
        __syncthreads();
#pragma unroll
        for (int i = 0; i < 4; i++) {
            int r = rl + 16 * i;
            int gm = m0 + r;
            float4 v = make_float4(0.f, 0.f, 0.f, 0.f);
            if (gm < M) v = *(const float4*)&x[(size_t)gm * K + k0 + c4];
            xs[c4 + 0][r] = v.x; xs[c4 + 1][r] = v.y;
            xs[c4 + 2][r] = v.z; xs[c4 + 3][r] = v.w;
            float4 w = *(const float4*)&w1[(size_t)(k0 + r) * 64 + c4];
            *(float4*)&ws[r][c4] = w;
        }
        __syncthreads();
#pragma unroll 16
        for (int kk = 0; kk < 64; kk++) {
            float4 a = *(const float4*)&xs[kk][rl * 4];
            float4 b = *(const float4*)&ws[kk][c4];
            float ar[4] = {a.x, a.y, a.z, a.w};
            float bc[4] = {b.x, b.y, b.z, b.w};
#pragma unroll
            for (int r = 0; r < 4; r++)
#pragma unroll
                for (int c = 0; c < 4; c++)
                    acc[r][c] = fmaf(ar[r], bc[c], acc[r][c]);
        }
    }
    float4 bb = *(const float4*)&b1[c4];
    float bias[4] = {bb.x, bb.y, bb.z, bb.w};
#pragma unroll
    for (int r = 0; r < 4; r++) {
        int gm = m0 + rl * 4 + r;
        if (gm < M) {
            float4 o;
            o.x = fmaxf(acc[r][0] + bias[0], 0.f);
            o.y = fmaxf(acc[r][1] + bias[1], 0.f);
            o.z = fmaxf(acc[r][2] + bias[2], 0.f);
            o.w = fmaxf(acc[r][3] + bias[3], 0.f);
            *(float4*)&t[(size_t)gm * 64 + c4] = o;
        }
    }
}

// ---------------------------------------------------------------------------
// GEMM 2: h = t @ w2 + b2  -> f32 into out[m*OS+n], bf16 copy into hb[m*Nc+n]
// ---------------------------------------------------------------------------
__global__ __launch_bounds__(256) void k_mlp2(const float* __restrict__ t,
                                              const float* __restrict__ w2,
                                              const float* __restrict__ b2,
                                              float* __restrict__ out,
                                              bfu* __restrict__ hb,
                                              int M, int Nc, int OS) {
    __shared__ float ts[64][68];
    __shared__ float ws[64][68];
    const int tid = threadIdx.x;
    const int m0 = blockIdx.x * 64;
    const int n0 = blockIdx.y * 64;
    const int rl = tid >> 4;
    const int c4 = (tid & 15) * 4;
    float acc[4][4] = {};

#pragma unroll
    for (int i = 0; i < 4; i++) {
        int r = rl + 16 * i;
        int gm = m0 + r;
        float4 v = make_float4(0.f, 0.f, 0.f, 0.f);
        if (gm < M) v = *(const float4*)&t[(size_t)gm * 64 + c4];
        ts[c4 + 0][r] = v.x; ts[c4 + 1][r] = v.y;
        ts[c4 + 2][r] = v.z; ts[c4 + 3][r] = v.w;
        float4 w = *(const float4*)&w2[(size_t)r * Nc + n0 + c4];
        *(float4*)&ws[r][c4] = w;
    }
    __syncthreads();
#pragma unroll 16
    for (int kk = 0; kk < 64; kk++) {
        float4 a = *(const float4*)&ts[kk][rl * 4];
        float4 b = *(const float4*)&ws[kk][c4];
        float ar[4] = {a.x, a.y, a.z, a.w};
        float bc[4] = {b.x, b.y, b.z, b.w};
#pragma unroll
        for (int r = 0; r < 4; r++)
#pragma unroll
            for (int c = 0; c < 4; c++)
                acc[r][c] = fmaf(ar[r], bc[c], acc[r][c]);
    }
    float4 bb = *(const float4*)&b2[n0 + c4];
    float bias[4] = {bb.x, bb.y, bb.z, bb.w};
#pragma unroll
    for (int r = 0; r < 4; r++) {
        int gm = m0 + rl * 4 + r;
        if (gm < M) {
            float4 o;
            o.x = acc[r][0] + bias[0];
            o.y = acc[r][1] + bias[1];
            o.z = acc[r][2] + bias[2];
            o.w = acc[r][3] + bias[3];
            *(float4*)&out[(size_t)gm * OS + n0 + c4] = o;
            ushort4 hq;
            hq.x = f2bf(o.x); hq.y = f2bf(o.y);
            hq.z = f2bf(o.z); hq.w = f2bf(o.w);
            *(ushort4*)&hb[(size_t)gm * Nc + n0 + c4] = hq;
        }
    }
}

// ---------------------------------------------------------------------------
// Aggregation: per-node max over incoming edges (CSR), wave per node.
// Gather table hb is dense bf16 [N, 64*R]; output f32 at `ostride`.
// 4-deep manual unroll: 4 independent row loads in flight.
// ---------------------------------------------------------------------------
template <int R>
__global__ void k_agg(const bfu* __restrict__ hb, float* __restrict__ aggr,
                      const int* __restrict__ rowptr, const int* __restrict__ colidx,
                      int N, int ostride) {
    const int wid = (blockIdx.x * blockDim.x + threadIdx.x) >> 6;
    const int lane = threadIdx.x & 63;
    if (wid >= N) return;
    const int beg = rowptr[wid], end = rowptr[wid + 1];
    const int cb = 64 * R;
    const int ch = lane * R;

    float acc[R];
#pragma unroll
    for (int r = 0; r < R; r++) acc[r] = -INFINITY;

    int i = beg;
    for (; i + 4 <= end; i += 4) {
        int s0 = colidx[i + 0], s1 = colidx[i + 1];
        int s2 = colidx[i + 2], s3 = colidx[i + 3];
        const bfu* p0 = hb + (size_t)s0 * cb + ch;
        const bfu* p1 = hb + (size_t)s1 * cb + ch;
        const bfu* p2 = hb + (size_t)s2 * cb + ch;
        const bfu* p3 = hb + (size_t)s3 * cb + ch;
        if (R == 4) {
            ushort4 v0 = *(const ushort4*)p0;
            ushort4 v1 = *(const ushort4*)p1;
            ushort4 v2 = *(const ushort4*)p2;
            ushort4 v3 = *(const ushort4*)p3;
            acc[0] = fmaxf(acc[0], fmaxf(fmaxf(b2f(v0.x), b2f(v1.x)), fmaxf(b2f(v2.x), b2f(v3.x))));
            acc[1] = fmaxf(acc[1], fmaxf(fmaxf(b2f(v0.y), b2f(v1.y)), fmaxf(b2f(v2.y), b2f(v3.y))));
            acc[2] = fmaxf(acc[2], fmaxf(fmaxf(b2f(v0.z), b2f(v1.z)), fmaxf(b2f(v2.z), b2f(v3.z))));
            acc[3] = fmaxf(acc[3], fmaxf(fmaxf(b2f(v0.w), b2f(v1.w)), fmaxf(b2f(v2.w), b2f(v3.w))));
        } else if (R == 2) {
            ushort2 v0 = *(const ushort2*)p0;
            ushort2 v1 = *(const ushort2*)p1;
            ushort2 v2 = *(const ushort2*)p2;
            ushort2 v3 = *(const ushort2*)p3;
            acc[0] = fmaxf(acc[0], fmaxf(fmaxf(b2f(v0.x), b2f(v1.x)), fmaxf(b2f(v2.x), b2f(v3.x))));
            acc[1] = fmaxf(acc[1], fmaxf(fmaxf(b2f(v0.y), b2f(v1.y)), fmaxf(b2f(v2.y), b2f(v3.y))));
        } else {
            bfu v0 = *p0, v1 = *p1, v2 = *p2, v3 = *p3;
            acc[0] = fmaxf(acc[0], fmaxf(fmaxf(b2f(v0), b2f(v1)), fmaxf(b2f(v2), b2f(v3))));
        }
    }
    for (; i < end; i++) {
        int s = colidx[i];
        const bfu* p = hb + (size_t)s * cb + ch;
        if (R == 4) {
            ushort4 v = *(const ushort4*)p;
            acc[0] = fmaxf(acc[0], b2f(v.x)); acc[1] = fmaxf(acc[1], b2f(v.y));
            acc[2] = fmaxf(acc[2], b2f(v.z)); acc[3] = fmaxf(acc[3], b2f(v.w));
        } else if (R == 2) {
            ushort2 v = *(const ushort2*)p;
            acc[0] = fmaxf(acc[0], b2f(v.x)); acc[1] = fmaxf(acc[1], b2f(v.y));
        } else {
            acc[0] = fmaxf(acc[0], b2f(*p));
        }
    }

    if (beg == end) {
#pragma unroll
        for (int r = 0; r < R; r++) acc[r] = 0.f;
    }
    float* q = aggr + (size_t)wid * ostride + ch;
#pragma unroll
    for (int r = 0; r < R; r++) q[r] = acc[r];
}

// ---------------------------------------------------------------------------
// Cluster max-pool + fused column sum-of-squares
// ---------------------------------------------------------------------------
__global__ void k_pool(const float* __restrict__ x3, const int* __restrict__ cptr,
                       const int* __restrict__ cidx, float* __restrict__ pooled,
                       float* __restrict__ sumsq) {
    int cl = blockIdx.x;
    int tid = threadIdx.x;
    int beg = cptr[cl], end = cptr[cl + 1];
    float ax = -INFINITY, ay = -INFINITY;
    for (int i = beg; i < end; i++) {
        int n = cidx[i];
        float2 v = *(const float2*)&x3[(size_t)n * 512 + tid * 2];
        ax = fmaxf(ax, v.x); ay = fmaxf(ay, v.y);
    }
    if (beg == end) { ax = 0.f; ay = 0.f; }
    float2 o; o.x = ax; o.y = ay;
    *(float2*)&pooled[(size_t)cl * 512 + tid * 2] = o;
    atomicAdd(&sumsq[tid * 2 + 0], ax * ax);
    atomicAdd(&sumsq[tid * 2 + 1], ay * ay);
}

__global__ void k_scale(const float* __restrict__ pooled, const float* __restrict__ sumsq,
                        float* __restrict__ out, int total) {
    int i = blockIdx.x * blockDim.x + threadIdx.x;
    int base = i * 4;
    if (base < total) {
        float4 v = *(const float4*)&pooled[base];
        int col = base & 511;
        v.x /= (sqrtf(sumsq[col + 0]) + 1e-6f);
        v.y /= (sqrtf(sumsq[col + 1]) + 1e-6f);
        v.z /= (sqrtf(sumsq[col + 2]) + 1e-6f);
        v.w /= (sqrtf(sumsq[col + 3]) + 1e-6f);
        *(float4*)&out[base] = v;
    }
}

// ---------------------------------------------------------------------------
extern "C" void kernel_launch(void* const* d_in, const int* in_sizes, int n_in,
                              void* d_out, int out_size, void* d_ws, size_t ws_size,
                              hipStream_t stream) {
    const float* x0      = (const float*)d_in[0];
    const int*   ei      = (const int*)d_in[1];
    const int*   cluster = (const int*)d_in[2];
    const float* w1_[3] = {(const float*)d_in[3], (const float*)d_in[7],  (const float*)d_in[11]};
    const float* b1_[3] = {(const float*)d_in[4], (const float*)d_in[8],  (const float*)d_in[12]};
    const float* w2_[3] = {(const float*)d_in[5], (const float*)d_in[9],  (const float*)d_in[13]};
    const float* b2_[3] = {(const float*)d_in[6], (const float*)d_in[10], (const float*)d_in[14]};

    const int N  = in_sizes[2];       // 50000
    const int E  = in_sizes[1] / 2;   // 800000
    const int NC = 2500;
    float* out = (float*)d_out;

    char* p = (char*)d_ws;
    auto alloc = [&](size_t bytes) -> char* {
        char* r = p;
        p += (bytes + 255) & ~(size_t)255;
        return r;
    };
    float* x1     = (float*)alloc((size_t)N * 128 * 4);
    float* x2     = (float*)alloc((size_t)N * 256 * 4);
    float* x3     = (float*)alloc((size_t)N * 512 * 4);
    float* tbuf   = (float*)alloc((size_t)N * 64 * 4);
    bfu*   hb0    = (bfu*)alloc((size_t)N * 64 * 2);
    bfu*   hb1    = (bfu*)alloc((size_t)N * 128 * 2);
    bfu*   hb2    = (bfu*)alloc((size_t)N * 256 * 2);
    float* pooled = (float*)alloc((size_t)NC * 512 * 4);
    float* sumsq  = (float*)alloc(512 * 4);
    int*   deg    = (int*)alloc((size_t)(N + 1) * 4);
    int*   rowptr = (int*)alloc((size_t)(N + 1) * 4);
    int*   cursor = (int*)alloc((size_t)(N + 1) * 4);
    int*   colidx = (int*)alloc((size_t)E * 4);
    int*   cdeg   = (int*)alloc((size_t)(NC + 1) * 4);
    int*   cptr   = (int*)alloc((size_t)(NC + 1) * 4);
    int*   ccur   = (int*)alloc((size_t)(NC + 1) * 4);
    int*   cidx   = (int*)alloc((size_t)N * 4);

    const int* src = ei;
    const int* dst = ei + E;

    k_zero3<<<(N + 255) / 256, 256, 0, stream>>>(deg, N, cdeg, NC, sumsq);

    // edge CSR (keyed by dst, storing src)
    k_hist<<<(E + 255) / 256, 256, 0, stream>>>(dst, E, deg);
    k_scan<<<1, 1024, 0, stream>>>(deg, N, rowptr, cursor);
    k_scatter_edges<<<(E + 255) / 256, 256, 0, stream>>>(dst, src, E, cursor, colidx);

    // cluster CSR
    k_hist<<<(N + 255) / 256, 256, 0, stream>>>(cluster, N, cdeg);
    k_scan<<<1, 1024, 0, stream>>>(cdeg, NC, cptr, ccur);
    k_scatter_nodes<<<(N + 255) / 256, 256, 0, stream>>>(cluster, N, ccur, cidx);

    const int Mtiles = (N + 63) / 64;
    const int aggBlocks = (N * 64 + 255) / 256;

    // layer 0: c=64
    k_mlp1<64><<<Mtiles, 256, 0, stream>>>(x0, w1_[0], b1_[0], tbuf, N);
    k_mlp2<<<dim3(Mtiles, 1), 256, 0, stream>>>(tbuf, w2_[0], b2_[0], x1, hb0, N, 64, 128);
    k_agg<1><<<aggBlocks, 256, 0, stream>>>(hb0, x1 + 64, rowptr, colidx, N, 128);

    // layer 1: c=128
    k_mlp1<128><<<Mtiles, 256, 0, stream>>>(x1, w1_[1], b1_[1], tbuf, N);
    k_mlp2<<<dim3(Mtiles, 2), 256, 0, stream>>>(tbuf, w2_[1], b2_[1], x2, hb1, N, 128, 256);
    k_agg<2><<<aggBlocks, 256, 0, stream>>>(hb1, x2 + 128, rowptr, colidx, N, 256);

    // layer 2: c=256
    k_mlp1<256><<<Mtiles, 256, 0, stream>>>(x2, w1_[2], b1_[2], tbuf, N);
    k_mlp2<<<dim3(Mtiles, 4), 256, 0, stream>>>(tbuf, w2_[2], b2_[2], x3, hb2, N, 256, 512);
    k_agg<4><<<aggBlocks, 256, 0, stream>>>(hb2, x3 + 256, rowptr, colidx, N, 512);

    // cluster max-pool + column norm
    k_pool<<<NC, 256, 0, stream>>>(x3, cptr, cidx, pooled, sumsq);
    k_scale<<<(out_size / 4 + 255) / 256, 256, 0, stream>>>(pooled, sumsq, out, out_size);
}

// Round 3
// 516.143 us; speedup vs baseline: 1.1988x; 1.1988x over previous
//
#include <hip/hip_runtime.h>
#include <math.h>

typedef unsigned short bfu;

__device__ __forceinline__ float b2f(bfu u) {
    unsigned int x = ((unsigned int)u) << 16;
    return __uint_as_float(x);
}
__device__ __forceinline__ bfu f2bf(float f) {
    unsigned int u = __float_as_uint(f);
    unsigned int r = (u + 0x7FFFu + ((u >> 16) & 1u)) >> 16;
    return (bfu)r;
}

// ---------------------------------------------------------------------------
// fused zero: deg[N], cdeg[NC], sumsq[512]
// ---------------------------------------------------------------------------
__global__ void k_zero3(int* __restrict__ deg, int N, int* __restrict__ cdeg, int NC,
                        float* __restrict__ sumsq) {
    int i = blockIdx.x * blockDim.x + threadIdx.x;
    if (i < N) deg[i] = 0;
    if (i < NC) cdeg[i] = 0;
    if (i < 512) sumsq[i] = 0.f;
}

// ---------------------------------------------------------------------------
// CSR build: histogram -> single-block scan -> scatter
// ---------------------------------------------------------------------------
__global__ void k_hist(const int* __restrict__ keys, int n, int* __restrict__ deg) {
    int i = blockIdx.x * blockDim.x + threadIdx.x;
    if (i < n) atomicAdd(&deg[keys[i]], 1);
}

__global__ void k_scan(const int* __restrict__ deg, int n,
                       int* __restrict__ ptr, int* __restrict__ cur) {
    __shared__ int part[1024];
    const int t = threadIdx.x;
    const int chunk = (n + 1023) / 1024;
    int b = t * chunk;
    int e = b + chunk; if (e > n) e = n;
    int s = 0;
    for (int i = b; i < e; i++) s += deg[i];
    part[t] = s;
    __syncthreads();
    for (int off = 1; off < 1024; off <<= 1) {
        int v = part[t];
        int u = (t >= off) ? part[t - off] : 0;
        __syncthreads();
        part[t] = v + u;
        __syncthreads();
    }
    int excl = (t == 0) ? 0 : part[t - 1];
    for (int i = b; i < e; i++) {
        ptr[i] = excl; cur[i] = excl;
        excl += deg[i];
    }
    if (t == 1023) ptr[n] = part[1023];
}

__global__ void k_scatter_edges(const int* __restrict__ dst, const int* __restrict__ src,
                                int E, int* __restrict__ cur, int* __restrict__ colidx) {
    int e = blockIdx.x * blockDim.x + threadIdx.x;
    if (e < E) {
        int d = dst[e];
        int pos = atomicAdd(&cur[d], 1);
        colidx[pos] = src[e];
    }
}

__global__ void k_scatter_nodes(const int* __restrict__ key, int N,
                                int* __restrict__ cur, int* __restrict__ idx) {
    int i = blockIdx.x * blockDim.x + threadIdx.x;
    if (i < N) {
        int c = key[i];
        int pos = atomicAdd(&cur[c], 1);
        idx[pos] = i;
    }
}

// ---------------------------------------------------------------------------
// GEMM 1: t = relu(x @ w1 + b1)   x:[M,K] (dense, stride K), w1:[K,64], t:[M,64]
// ---------------------------------------------------------------------------
template <int K>
__global__ __launch_bounds__(256) void k_mlp1(const float* __restrict__ x,
                                              const float* __restrict__ w1,
                                              const float* __restrict__ b1,
                                              float* __restrict__ t, int M) {
    __shared__ float xs[64][68];
    __shared__ float ws[64][68];
    const int tid = threadIdx.x;
    const int m0 = blockIdx.x * 64;
    const int rl = tid >> 4;
    const int c4 = (tid & 15) * 4;
    float acc[4][4] = {};

    for (int k0 = 0; k0 < K; k0 += 64) {
        __syncthreads();
#pragma unroll
        for (int i = 0; i < 4; i++) {
            int r = rl + 16 * i;
            int gm = m0 + r;
            float4 v = make_float4(0.f, 0.f, 0.f, 0.f);
            if (gm < M) v = *(const float4*)&x[(size_t)gm * K + k0 + c4];
            xs[c4 + 0][r] = v.x; xs[c4 + 1][r] = v.y;
            xs[c4 + 2][r] = v.z; xs[c4 + 3][r] = v.w;
            float4 w = *(const float4*)&w1[(size_t)(k0 + r) * 64 + c4];
            *(float4*)&ws[r][c4] = w;
        }
        __syncthreads();
#pragma unroll 16
        for (int kk = 0; kk < 64; kk++) {
            float4 a = *(const float4*)&xs[kk][rl * 4];
            float4 b = *(const float4*)&ws[kk][c4];
            float ar[4] = {a.x, a.y, a.z, a.w};
            float bc[4] = {b.x, b.y, b.z, b.w};
#pragma unroll
            for (int r = 0; r < 4; r++)
#pragma unroll
                for (int c = 0; c < 4; c++)
                    acc[r][c] = fmaf(ar[r], bc[c], acc[r][c]);
        }
    }
    float4 bb = *(const float4*)&b1[c4];
    float bias[4] = {bb.x, bb.y, bb.z, bb.w};
#pragma unroll
    for (int r = 0; r < 4; r++) {
        int gm = m0 + rl * 4 + r;
        if (gm < M) {
            float4 o;
            o.x = fmaxf(acc[r][0] + bias[0], 0.f);
            o.y = fmaxf(acc[r][1] + bias[1], 0.f);
            o.z = fmaxf(acc[r][2] + bias[2], 0.f);
            o.w = fmaxf(acc[r][3] + bias[3], 0.f);
            *(float4*)&t[(size_t)gm * 64 + c4] = o;
        }
    }
}

// ---------------------------------------------------------------------------
// GEMM 2: h = t @ w2 + b2  -> f32 into out[m*OS+n], bf16 copy into hb[m*Nc+n]
// ---------------------------------------------------------------------------
__global__ __launch_bounds__(256) void k_mlp2(const float* __restrict__ t,
                                              const float* __restrict__ w2,
                                              const float* __restrict__ b2,
                                              float* __restrict__ out,
                                              bfu* __restrict__ hb,
                                              int M, int Nc, int OS) {
    __shared__ float ts[64][68];
    __shared__ float ws[64][68];
    const int tid = threadIdx.x;
    const int m0 = blockIdx.x * 64;
    const int n0 = blockIdx.y * 64;
    const int rl = tid >> 4;
    const int c4 = (tid & 15) * 4;
    float acc[4][4] = {};

#pragma unroll
    for (int i = 0; i < 4; i++) {
        int r = rl + 16 * i;
        int gm = m0 + r;
        float4 v = make_float4(0.f, 0.f, 0.f, 0.f);
        if (gm < M) v = *(const float4*)&t[(size_t)gm * 64 + c4];
        ts[c4 + 0][r] = v.x; ts[c4 + 1][r] = v.y;
        ts[c4 + 2][r] = v.z; ts[c4 + 3][r] = v.w;
        float4 w = *(const float4*)&w2[(size_t)r * Nc + n0 + c4];
        *(float4*)&ws[r][c4] = w;
    }
    __syncthreads();
#pragma unroll 16
    for (int kk = 0; kk < 64; kk++) {
        float4 a = *(const float4*)&ts[kk][rl * 4];
        float4 b = *(const float4*)&ws[kk][c4];
        float ar[4] = {a.x, a.y, a.z, a.w};
        float bc[4] = {b.x, b.y, b.z, b.w};
#pragma unroll
        for (int r = 0; r < 4; r++)
#pragma unroll
            for (int c = 0; c < 4; c++)
                acc[r][c] = fmaf(ar[r], bc[c], acc[r][c]);
    }
    float4 bb = *(const float4*)&b2[n0 + c4];
    float bias[4] = {bb.x, bb.y, bb.z, bb.w};
#pragma unroll
    for (int r = 0; r < 4; r++) {
        int gm = m0 + rl * 4 + r;
        if (gm < M) {
            float4 o;
            o.x = acc[r][0] + bias[0];
            o.y = acc[r][1] + bias[1];
            o.z = acc[r][2] + bias[2];
            o.w = acc[r][3] + bias[3];
            *(float4*)&out[(size_t)gm * OS + n0 + c4] = o;
            ushort4 hq;
            hq.x = f2bf(o.x); hq.y = f2bf(o.y);
            hq.z = f2bf(o.z); hq.w = f2bf(o.w);
            *(ushort4*)&hb[(size_t)gm * Nc + n0 + c4] = hq;
        }
    }
}

// ---------------------------------------------------------------------------
// Aggregation: per-node max over incoming edges (CSR), wave per node.
// Gather table hb is dense bf16 [N, 64*R]; output f32 at `ostride`.
// ---------------------------------------------------------------------------
template <int R>
__global__ void k_agg(const bfu* __restrict__ hb, float* __restrict__ aggr,
                      const int* __restrict__ rowptr, const int* __restrict__ colidx,
                      int N, int ostride) {
    const int wid = (blockIdx.x * blockDim.x + threadIdx.x) >> 6;
    const int lane = threadIdx.x & 63;
    if (wid >= N) return;
    const int beg = rowptr[wid], end = rowptr[wid + 1];
    const int cb = 64 * R;
    const int ch = lane * R;

    float acc[R];
#pragma unroll
    for (int r = 0; r < R; r++) acc[r] = -INFINITY;

    int i = beg;
    for (; i + 4 <= end; i += 4) {
        int s0 = colidx[i + 0], s1 = colidx[i + 1];
        int s2 = colidx[i + 2], s3 = colidx[i + 3];
        const bfu* p0 = hb + (size_t)s0 * cb + ch;
        const bfu* p1 = hb + (size_t)s1 * cb + ch;
        const bfu* p2 = hb + (size_t)s2 * cb + ch;
        const bfu* p3 = hb + (size_t)s3 * cb + ch;
        if (R == 4) {
            ushort4 v0 = *(const ushort4*)p0;
            ushort4 v1 = *(const ushort4*)p1;
            ushort4 v2 = *(const ushort4*)p2;
            ushort4 v3 = *(const ushort4*)p3;
            acc[0] = fmaxf(acc[0], fmaxf(fmaxf(b2f(v0.x), b2f(v1.x)), fmaxf(b2f(v2.x), b2f(v3.x))));
            acc[1] = fmaxf(acc[1], fmaxf(fmaxf(b2f(v0.y), b2f(v1.y)), fmaxf(b2f(v2.y), b2f(v3.y))));
            acc[2] = fmaxf(acc[2], fmaxf(fmaxf(b2f(v0.z), b2f(v1.z)), fmaxf(b2f(v2.z), b2f(v3.z))));
            acc[3] = fmaxf(acc[3], fmaxf(fmaxf(b2f(v0.w), b2f(v1.w)), fmaxf(b2f(v2.w), b2f(v3.w))));
        } else if (R == 2) {
            ushort2 v0 = *(const ushort2*)p0;
            ushort2 v1 = *(const ushort2*)p1;
            ushort2 v2 = *(const ushort2*)p2;
            ushort2 v3 = *(const ushort2*)p3;
            acc[0] = fmaxf(acc[0], fmaxf(fmaxf(b2f(v0.x), b2f(v1.x)), fmaxf(b2f(v2.x), b2f(v3.x))));
            acc[1] = fmaxf(acc[1], fmaxf(fmaxf(b2f(v0.y), b2f(v1.y)), fmaxf(b2f(v2.y), b2f(v3.y))));
        } else {
            bfu v0 = *p0, v1 = *p1, v2 = *p2, v3 = *p3;
            acc[0] = fmaxf(acc[0], fmaxf(fmaxf(b2f(v0), b2f(v1)), fmaxf(b2f(v2), b2f(v3))));
        }
    }
    for (; i < end; i++) {
        int s = colidx[i];
        const bfu* p = hb + (size_t)s * cb + ch;
        if (R == 4) {
            ushort4 v = *(const ushort4*)p;
            acc[0] = fmaxf(acc[0], b2f(v.x)); acc[1] = fmaxf(acc[1], b2f(v.y));
            acc[2] = fmaxf(acc[2], b2f(v.z)); acc[3] = fmaxf(acc[3], b2f(v.w));
        } else if (R == 2) {
            ushort2 v = *(const ushort2*)p;
            acc[0] = fmaxf(acc[0], b2f(v.x)); acc[1] = fmaxf(acc[1], b2f(v.y));
        } else {
            acc[0] = fmaxf(acc[0], b2f(*p));
        }
    }

    if (beg == end) {
#pragma unroll
        for (int r = 0; r < R; r++) acc[r] = 0.f;
    }
    float* q = aggr + (size_t)wid * ostride + ch;
#pragma unroll
    for (int r = 0; r < R; r++) q[r] = acc[r];
}

// ---------------------------------------------------------------------------
// Cluster max-pool: block per cluster, 256 thr x float2; 4-deep unrolled gather
// ---------------------------------------------------------------------------
__global__ void k_pool(const float* __restrict__ x3, const int* __restrict__ cptr,
                       const int* __restrict__ cidx, float* __restrict__ pooled) {
    int cl = blockIdx.x;
    int tid = threadIdx.x;
    int beg = cptr[cl], end = cptr[cl + 1];
    float ax = -INFINITY, ay = -INFINITY;
    int i = beg;
    for (; i + 4 <= end; i += 4) {
        int n0 = cidx[i + 0], n1 = cidx[i + 1];
        int n2 = cidx[i + 2], n3 = cidx[i + 3];
        float2 v0 = *(const float2*)&x3[(size_t)n0 * 512 + tid * 2];
        float2 v1 = *(const float2*)&x3[(size_t)n1 * 512 + tid * 2];
        float2 v2 = *(const float2*)&x3[(size_t)n2 * 512 + tid * 2];
        float2 v3 = *(const float2*)&x3[(size_t)n3 * 512 + tid * 2];
        ax = fmaxf(ax, fmaxf(fmaxf(v0.x, v1.x), fmaxf(v2.x, v3.x)));
        ay = fmaxf(ay, fmaxf(fmaxf(v0.y, v1.y), fmaxf(v2.y, v3.y)));
    }
    for (; i < end; i++) {
        int n = cidx[i];
        float2 v = *(const float2*)&x3[(size_t)n * 512 + tid * 2];
        ax = fmaxf(ax, v.x); ay = fmaxf(ay, v.y);
    }
    if (beg == end) { ax = 0.f; ay = 0.f; }
    float2 o; o.x = ax; o.y = ay;
    *(float2*)&pooled[(size_t)cl * 512 + tid * 2] = o;
}

// ---------------------------------------------------------------------------
// Column-wise sum of squares (axis 0), low-contention (64 blocks)
// ---------------------------------------------------------------------------
__global__ void k_sumsq(const float* __restrict__ pooled, float* __restrict__ sumsq, int NC) {
    int tid = threadIdx.x;  // 256 threads, 2 cols each
    float ax = 0.f, ay = 0.f;
    for (int r = blockIdx.x; r < NC; r += gridDim.x) {
        float2 v = *(const float2*)&pooled[(size_t)r * 512 + tid * 2];
        ax += v.x * v.x; ay += v.y * v.y;
    }
    atomicAdd(&sumsq[tid * 2 + 0], ax);
    atomicAdd(&sumsq[tid * 2 + 1], ay);
}

__global__ void k_scale(const float* __restrict__ pooled, const float* __restrict__ sumsq,
                        float* __restrict__ out, int total) {
    int i = blockIdx.x * blockDim.x + threadIdx.x;
    int base = i * 4;
    if (base < total) {
        float4 v = *(const float4*)&pooled[base];
        int col = base & 511;
        v.x /= (sqrtf(sumsq[col + 0]) + 1e-6f);
        v.y /= (sqrtf(sumsq[col + 1]) + 1e-6f);
        v.z /= (sqrtf(sumsq[col + 2]) + 1e-6f);
        v.w /= (sqrtf(sumsq[col + 3]) + 1e-6f);
        *(float4*)&out[base] = v;
    }
}

// ---------------------------------------------------------------------------
extern "C" void kernel_launch(void* const* d_in, const int* in_sizes, int n_in,
                              void* d_out, int out_size, void* d_ws, size_t ws_size,
                              hipStream_t stream) {
    const float* x0      = (const float*)d_in[0];
    const int*   ei      = (const int*)d_in[1];
    const int*   cluster = (const int*)d_in[2];
    const float* w1_[3] = {(const float*)d_in[3], (const float*)d_in[7],  (const float*)d_in[11]};
    const float* b1_[3] = {(const float*)d_in[4], (const float*)d_in[8],  (const float*)d_in[12]};
    const float* w2_[3] = {(const float*)d_in[5], (const float*)d_in[9],  (const float*)d_in[13]};
    const float* b2_[3] = {(const float*)d_in[6], (const float*)d_in[10], (const float*)d_in[14]};

    const int N  = in_sizes[2];       // 50000
    const int E  = in_sizes[1] / 2;   // 800000
    const int NC = 2500;
    float* out = (float*)d_out;

    char* p = (char*)d_ws;
    auto alloc = [&](size_t bytes) -> char* {
        char* r = p;
        p += (bytes + 255) & ~(size_t)255;
        return r;
    };
    float* x1     = (float*)alloc((size_t)N * 128 * 4);
    float* x2     = (float*)alloc((size_t)N * 256 * 4);
    float* x3     = (float*)alloc((size_t)N * 512 * 4);
    float* tbuf   = (float*)alloc((size_t)N * 64 * 4);
    bfu*   hb0    = (bfu*)alloc((size_t)N * 64 * 2);
    bfu*   hb1    = (bfu*)alloc((size_t)N * 128 * 2);
    bfu*   hb2    = (bfu*)alloc((size_t)N * 256 * 2);
    float* pooled = (float*)alloc((size_t)NC * 512 * 4);
    float* sumsq  = (float*)alloc(512 * 4);
    int*   deg    = (int*)alloc((size_t)(N + 1) * 4);
    int*   rowptr = (int*)alloc((size_t)(N + 1) * 4);
    int*   cursor = (int*)alloc((size_t)(N + 1) * 4);
    int*   colidx = (int*)alloc((size_t)E * 4);
    int*   cdeg   = (int*)alloc((size_t)(NC + 1) * 4);
    int*   cptr   = (int*)alloc((size_t)(NC + 1) * 4);
    int*   ccur   = (int*)alloc((size_t)(NC + 1) * 4);
    int*   cidx   = (int*)alloc((size_t)N * 4);

    const int* src = ei;
    const int* dst = ei + E;

    k_zero3<<<(N + 255) / 256, 256, 0, stream>>>(deg, N, cdeg, NC, sumsq);

    // edge CSR (keyed by dst, storing src)
    k_hist<<<(E + 255) / 256, 256, 0, stream>>>(dst, E, deg);
    k_scan<<<1, 1024, 0, stream>>>(deg, N, rowptr, cursor);
    k_scatter_edges<<<(E + 255) / 256, 256, 0, stream>>>(dst, src, E, cursor, colidx);

    // cluster CSR
    k_hist<<<(N + 255) / 256, 256, 0, stream>>>(cluster, N, cdeg);
    k_scan<<<1, 1024, 0, stream>>>(cdeg, NC, cptr, ccur);
    k_scatter_nodes<<<(N + 255) / 256, 256, 0, stream>>>(cluster, N, ccur, cidx);

    const int Mtiles = (N + 63) / 64;
    const int aggBlocks = (N * 64 + 255) / 256;

    // layer 0: c=64
    k_mlp1<64><<<Mtiles, 256, 0, stream>>>(x0, w1_[0], b1_[0], tbuf, N);
    k_mlp2<<<dim3(Mtiles, 1), 256, 0, stream>>>(tbuf, w2_[0], b2_[0], x1, hb0, N, 64, 128);
    k_agg<1><<<aggBlocks, 256, 0, stream>>>(hb0, x1 + 64, rowptr, colidx, N, 128);

    // layer 1: c=128
    k_mlp1<128><<<Mtiles, 256, 0, stream>>>(x1, w1_[1], b1_[1], tbuf, N);
    k_mlp2<<<dim3(Mtiles, 2), 256, 0, stream>>>(tbuf, w2_[1], b2_[1], x2, hb1, N, 128, 256);
    k_agg<2><<<aggBlocks, 256, 0, stream>>>(hb1, x2 + 128, rowptr, colidx, N, 256);

    // layer 2: c=256
    k_mlp1<256><<<Mtiles, 256, 0, stream>>>(x2, w1_[2], b1_[2], tbuf, N);
    k_mlp2<<<dim3(Mtiles, 4), 256, 0, stream>>>(tbuf, w2_[2], b2_[2], x3, hb2, N, 256, 512);
    k_agg<4><<<aggBlocks, 256, 0, stream>>>(hb2, x3 + 256, rowptr, colidx, N, 512);

    // cluster max-pool + column norm
    k_pool<<<NC, 256, 0, stream>>>(x3, cptr, cidx, pooled);
    k_sumsq<<<64, 256, 0, stream>>>(pooled, sumsq, NC);
    k_scale<<<(out_size / 4 + 255) / 256, 256, 0, stream>>>(pooled, sumsq, out, out_size);
}

// Round 4
// 417.933 us; speedup vs baseline: 1.4805x; 1.2350x over previous
//
#include <hip/hip_runtime.h>
#include <math.h>

typedef unsigned short bfu;

__device__ __forceinline__ float b2f(bfu u) {
    unsigned int x = ((unsigned int)u) << 16;
    return __uint_as_float(x);
}
__device__ __forceinline__ bfu f2bf(float f) {
    unsigned int u = __float_as_uint(f);
    unsigned int r = (u + 0x7FFFu + ((u >> 16) & 1u)) >> 16;
    return (bfu)r;
}

// ---------------------------------------------------------------------------
// fused zero: deg[N], cdeg[NC], sumsq[512]
// ---------------------------------------------------------------------------
__global__ void k_zero3(int* __restrict__ deg, int N, int* __restrict__ cdeg, int NC,
                        float* __restrict__ sumsq) {
    int i = blockIdx.x * blockDim.x + threadIdx.x;
    if (i < N) deg[i] = 0;
    if (i < NC) cdeg[i] = 0;
    if (i < 512) sumsq[i] = 0.f;
}

// ---------------------------------------------------------------------------
// CSR build: histogram -> hierarchical scan -> scatter
// ---------------------------------------------------------------------------
__global__ void k_hist(const int* __restrict__ keys, int n, int* __restrict__ deg) {
    int i = blockIdx.x * blockDim.x + threadIdx.x;
    if (i < n) atomicAdd(&deg[keys[i]], 1);
}

// Phase A: per-block (256-wide) inclusive scan; store inclusive + block sum.
// blockIdx.y selects segment: 0 -> deg[N], 1 -> cdeg[NC]
__global__ __launch_bounds__(256) void k_scanA(const int* __restrict__ deg, int N,
                                               const int* __restrict__ cdeg, int NC,
                                               int* __restrict__ scn0, int* __restrict__ scn1,
                                               int* __restrict__ bsum0, int* __restrict__ bsum1) {
    __shared__ int part[256];
    const int seg = blockIdx.y;
    const int n = seg ? NC : N;
    const int* d = seg ? cdeg : deg;
    int* scn = seg ? scn1 : scn0;
    int* bs  = seg ? bsum1 : bsum0;
    const int b = blockIdx.x;
    if (b * 256 >= n) return;
    const int t = threadIdx.x;
    const int i = b * 256 + t;
    int v = (i < n) ? d[i] : 0;
    part[t] = v;
    __syncthreads();
#pragma unroll
    for (int off = 1; off < 256; off <<= 1) {
        int cv = part[t];
        int u = (t >= off) ? part[t - off] : 0;
        __syncthreads();
        part[t] = cv + u;
        __syncthreads();
    }
    if (i < n) scn[i] = part[t];
    if (t == 255) bs[b] = part[255];
}

// Phase B: single block, exclusive-scan the block sums for both segments.
__global__ __launch_bounds__(256) void k_scanB(int* __restrict__ bsum0, int nb0,
                                               int* __restrict__ bsum1, int nb1,
                                               int* __restrict__ ptr0, int N,
                                               int* __restrict__ ptr1, int NC) {
    __shared__ int part[256];
    const int t = threadIdx.x;
    // segment 0
    int v = (t < nb0) ? bsum0[t] : 0;
    part[t] = v;
    __syncthreads();
#pragma unroll
    for (int off = 1; off < 256; off <<= 1) {
        int cv = part[t];
        int u = (t >= off) ? part[t - off] : 0;
        __syncthreads();
        part[t] = cv + u;
        __syncthreads();
    }
    if (t < nb0) bsum0[t] = part[t] - v;
    if (t == 255) ptr0[N] = part[255];
    __syncthreads();
    // segment 1
    v = (t < nb1) ? bsum1[t] : 0;
    part[t] = v;
    __syncthreads();
#pragma unroll
    for (int off = 1; off < 256; off <<= 1) {
        int cv = part[t];
        int u = (t >= off) ? part[t - off] : 0;
        __syncthreads();
        part[t] = cv + u;
        __syncthreads();
    }
    if (t < nb1) bsum1[t] = part[t] - v;
    if (t == 255) ptr1[NC] = part[255];
}

// Phase C: ptr[i] = blockoff + incl[i] - d[i]  (exclusive), dup into cursor.
__global__ __launch_bounds__(256) void k_scanC(const int* __restrict__ deg, int N,
                                               const int* __restrict__ cdeg, int NC,
                                               const int* __restrict__ scn0, const int* __restrict__ scn1,
                                               const int* __restrict__ bsum0, const int* __restrict__ bsum1,
                                               int* __restrict__ ptr0, int* __restrict__ cur0,
                                               int* __restrict__ ptr1, int* __restrict__ cur1) {
    const int seg = blockIdx.y;
    const int n = seg ? NC : N;
    const int* d = seg ? cdeg : deg;
    const int* scn = seg ? scn1 : scn0;
    const int* bs  = seg ? bsum1 : bsum0;
    int* ptr = seg ? ptr1 : ptr0;
    int* cur = seg ? cur1 : cur0;
    const int b = blockIdx.x;
    if (b * 256 >= n) return;
    const int i = b * 256 + threadIdx.x;
    if (i < n) {
        int e = bs[b] + scn[i] - d[i];
        ptr[i] = e;
        cur[i] = e;
    }
}

__global__ void k_scatter_edges(const int* __restrict__ dst, const int* __restrict__ src,
                                int E, int* __restrict__ cur, int* __restrict__ colidx) {
    int e = blockIdx.x * blockDim.x + threadIdx.x;
    if (e < E) {
        int d = dst[e];
        int pos = atomicAdd(&cur[d], 1);
        colidx[pos] = src[e];
    }
}

__global__ void k_scatter_nodes(const int* __restrict__ key, int N,
                                int* __restrict__ cur, int* __restrict__ idx) {
    int i = blockIdx.x * blockDim.x + threadIdx.x;
    if (i < N) {
        int c = key[i];
        int pos = atomicAdd(&cur[c], 1);
        idx[pos] = i;
    }
}

// ---------------------------------------------------------------------------
// GEMM 1: t = relu(x @ w1 + b1)   x:[M,K] (dense, stride K), w1:[K,64], t:[M,64]
// ---------------------------------------------------------------------------
template <int K>
__global__ __launch_bounds__(256) void k_mlp1(const float* __restrict__ x,
                                              const float* __restrict__ w1,
                                              const float* __restrict__ b1,
                                              float* __restrict__ t, int M) {
    __shared__ float xs[64][68];
    __shared__ float ws[64][68];
    const int tid = threadIdx.x;
    const int m0 = blockIdx.x * 64;
    const int rl = tid >> 4;
    const int c4 = (tid & 15) * 4;
    float acc[4][4] = {};

    for (int k0 = 0; k0 < K; k0 += 64) {
        __syncthreads();
#pragma unroll
        for (int i = 0; i < 4; i++) {
            int r = rl + 16 * i;
            int gm = m0 + r;
            float4 v = make_float4(0.f, 0.f, 0.f, 0.f);
            if (gm < M) v = *(const float4*)&x[(size_t)gm * K + k0 + c4];
            xs[c4 + 0][r] = v.x; xs[c4 + 1][r] = v.y;
            xs[c4 + 2][r] = v.z; xs[c4 + 3][r] = v.w;
            float4 w = *(const float4*)&w1[(size_t)(k0 + r) * 64 + c4];
            *(float4*)&ws[r][c4] = w;
        }
        __syncthreads();
#pragma unroll 16
        for (int kk = 0; kk < 64; kk++) {
            float4 a = *(const float4*)&xs[kk][rl * 4];
            float4 b = *(const float4*)&ws[kk][c4];
            float ar[4] = {a.x, a.y, a.z, a.w};
            float bc[4] = {b.x, b.y, b.z, b.w};
#pragma unroll
            for (int r = 0; r < 4; r++)
#pragma unroll
                for (int c = 0; c < 4; c++)
                    acc[r][c] = fmaf(ar[r], bc[c], acc[r][c]);
        }
    }
    float4 bb = *(const float4*)&b1[c4];
    float bias[4] = {bb.x, bb.y, bb.z, bb.w};
#pragma unroll
    for (int r = 0; r < 4; r++) {
        int gm = m0 + rl * 4 + r;
        if (gm < M) {
            float4 o;
            o.x = fmaxf(acc[r][0] + bias[0], 0.f);
            o.y = fmaxf(acc[r][1] + bias[1], 0.f);
            o.z = fmaxf(acc[r][2] + bias[2], 0.f);
            o.w = fmaxf(acc[r][3] + bias[3], 0.f);
            *(float4*)&t[(size_t)gm * 64 + c4] = o;
        }
    }
}

// ---------------------------------------------------------------------------
// GEMM 2: h = t @ w2 + b2  -> f32 into out[m*OS+n], bf16 copy into hb[m*Nc+n]
// ---------------------------------------------------------------------------
__global__ __launch_bounds__(256) void k_mlp2(const float* __restrict__ t,
                                              const float* __restrict__ w2,
                                              const float* __restrict__ b2,
                                              float* __restrict__ out,
                                              bfu* __restrict__ hb,
                                              int M, int Nc, int OS) {
    __shared__ float ts[64][68];
    __shared__ float ws[64][68];
    const int tid = threadIdx.x;
    const int m0 = blockIdx.x * 64;
    const int n0 = blockIdx.y * 64;
    const int rl = tid >> 4;
    const int c4 = (tid & 15) * 4;
    float acc[4][4] = {};

#pragma unroll
    for (int i = 0; i < 4; i++) {
        int r = rl + 16 * i;
        int gm = m0 + r;
        float4 v = make_float4(0.f, 0.f, 0.f, 0.f);
        if (gm < M) v = *(const float4*)&t[(size_t)gm * 64 + c4];
        ts[c4 + 0][r] = v.x; ts[c4 + 1][r] = v.y;
        ts[c4 + 2][r] = v.z; ts[c4 + 3][r] = v.w;
        float4 w = *(const float4*)&w2[(size_t)r * Nc + n0 + c4];
        *(float4*)&ws[r][c4] = w;
    }
    __syncthreads();
#pragma unroll 16
    for (int kk = 0; kk < 64; kk++) {
        float4 a = *(const float4*)&ts[kk][rl * 4];
        float4 b = *(const float4*)&ws[kk][c4];
        float ar[4] = {a.x, a.y, a.z, a.w};
        float bc[4] = {b.x, b.y, b.z, b.w};
#pragma unroll
        for (int r = 0; r < 4; r++)
#pragma unroll
            for (int c = 0; c < 4; c++)
                acc[r][c] = fmaf(ar[r], bc[c], acc[r][c]);
    }
    float4 bb = *(const float4*)&b2[n0 + c4];
    float bias[4] = {bb.x, bb.y, bb.z, bb.w};
#pragma unroll
    for (int r = 0; r < 4; r++) {
        int gm = m0 + rl * 4 + r;
        if (gm < M) {
            float4 o;
            o.x = acc[r][0] + bias[0];
            o.y = acc[r][1] + bias[1];
            o.z = acc[r][2] + bias[2];
            o.w = acc[r][3] + bias[3];
            *(float4*)&out[(size_t)gm * OS + n0 + c4] = o;
            ushort4 hq;
            hq.x = f2bf(o.x); hq.y = f2bf(o.y);
            hq.z = f2bf(o.z); hq.w = f2bf(o.w);
            *(ushort4*)&hb[(size_t)gm * Nc + n0 + c4] = hq;
        }
    }
}

// ---------------------------------------------------------------------------
// Aggregation: per-node max over incoming edges (CSR), wave per node.
// Gather table hb is dense bf16 [N, 64*R]; output f32 at `ostride`.
// ---------------------------------------------------------------------------
template <int R>
__global__ void k_agg(const bfu* __restrict__ hb, float* __restrict__ aggr,
                      const int* __restrict__ rowptr, const int* __restrict__ colidx,
                      int N, int ostride) {
    const int wid = (blockIdx.x * blockDim.x + threadIdx.x) >> 6;
    const int lane = threadIdx.x & 63;
    if (wid >= N) return;
    const int beg = rowptr[wid], end = rowptr[wid + 1];
    const int cb = 64 * R;
    const int ch = lane * R;

    float acc[R];
#pragma unroll
    for (int r = 0; r < R; r++) acc[r] = -INFINITY;

    int i = beg;
    for (; i + 4 <= end; i += 4) {
        int s0 = colidx[i + 0], s1 = colidx[i + 1];
        int s2 = colidx[i + 2], s3 = colidx[i + 3];
        const bfu* p0 = hb + (size_t)s0 * cb + ch;
        const bfu* p1 = hb + (size_t)s1 * cb + ch;
        const bfu* p2 = hb + (size_t)s2 * cb + ch;
        const bfu* p3 = hb + (size_t)s3 * cb + ch;
        if (R == 4) {
            ushort4 v0 = *(const ushort4*)p0;
            ushort4 v1 = *(const ushort4*)p1;
            ushort4 v2 = *(const ushort4*)p2;
            ushort4 v3 = *(const ushort4*)p3;
            acc[0] = fmaxf(acc[0], fmaxf(fmaxf(b2f(v0.x), b2f(v1.x)), fmaxf(b2f(v2.x), b2f(v3.x))));
            acc[1] = fmaxf(acc[1], fmaxf(fmaxf(b2f(v0.y), b2f(v1.y)), fmaxf(b2f(v2.y), b2f(v3.y))));
            acc[2] = fmaxf(acc[2], fmaxf(fmaxf(b2f(v0.z), b2f(v1.z)), fmaxf(b2f(v2.z), b2f(v3.z))));
            acc[3] = fmaxf(acc[3], fmaxf(fmaxf(b2f(v0.w), b2f(v1.w)), fmaxf(b2f(v2.w), b2f(v3.w))));
        } else if (R == 2) {
            ushort2 v0 = *(const ushort2*)p0;
            ushort2 v1 = *(const ushort2*)p1;
            ushort2 v2 = *(const ushort2*)p2;
            ushort2 v3 = *(const ushort2*)p3;
            acc[0] = fmaxf(acc[0], fmaxf(fmaxf(b2f(v0.x), b2f(v1.x)), fmaxf(b2f(v2.x), b2f(v3.x))));
            acc[1] = fmaxf(acc[1], fmaxf(fmaxf(b2f(v0.y), b2f(v1.y)), fmaxf(b2f(v2.y), b2f(v3.y))));
        } else {
            bfu v0 = *p0, v1 = *p1, v2 = *p2, v3 = *p3;
            acc[0] = fmaxf(acc[0], fmaxf(fmaxf(b2f(v0), b2f(v1)), fmaxf(b2f(v2), b2f(v3))));
        }
    }
    for (; i < end; i++) {
        int s = colidx[i];
        const bfu* p = hb + (size_t)s * cb + ch;
        if (R == 4) {
            ushort4 v = *(const ushort4*)p;
            acc[0] = fmaxf(acc[0], b2f(v.x)); acc[1] = fmaxf(acc[1], b2f(v.y));
            acc[2] = fmaxf(acc[2], b2f(v.z)); acc[3] = fmaxf(acc[3], b2f(v.w));
        } else if (R == 2) {
            ushort2 v = *(const ushort2*)p;
            acc[0] = fmaxf(acc[0], b2f(v.x)); acc[1] = fmaxf(acc[1], b2f(v.y));
        } else {
            acc[0] = fmaxf(acc[0], b2f(*p));
        }
    }

    if (beg == end) {
#pragma unroll
        for (int r = 0; r < R; r++) acc[r] = 0.f;
    }
    float* q = aggr + (size_t)wid * ostride + ch;
#pragma unroll
    for (int r = 0; r < R; r++) q[r] = acc[r];
}

// ---------------------------------------------------------------------------
// Cluster max-pool: block per cluster, 256 thr x float2; 4-deep unrolled gather
// ---------------------------------------------------------------------------
__global__ void k_pool(const float* __restrict__ x3, const int* __restrict__ cptr,
                       const int* __restrict__ cidx, float* __restrict__ pooled) {
    int cl = blockIdx.x;
    int tid = threadIdx.x;
    int beg = cptr[cl], end = cptr[cl + 1];
    float ax = -INFINITY, ay = -INFINITY;
    int i = beg;
    for (; i + 4 <= end; i += 4) {
        int n0 = cidx[i + 0], n1 = cidx[i + 1];
        int n2 = cidx[i + 2], n3 = cidx[i + 3];
        float2 v0 = *(const float2*)&x3[(size_t)n0 * 512 + tid * 2];
        float2 v1 = *(const float2*)&x3[(size_t)n1 * 512 + tid * 2];
        float2 v2 = *(const float2*)&x3[(size_t)n2 * 512 + tid * 2];
        float2 v3 = *(const float2*)&x3[(size_t)n3 * 512 + tid * 2];
        ax = fmaxf(ax, fmaxf(fmaxf(v0.x, v1.x), fmaxf(v2.x, v3.x)));
        ay = fmaxf(ay, fmaxf(fmaxf(v0.y, v1.y), fmaxf(v2.y, v3.y)));
    }
    for (; i < end; i++) {
        int n = cidx[i];
        float2 v = *(const float2*)&x3[(size_t)n * 512 + tid * 2];
        ax = fmaxf(ax, v.x); ay = fmaxf(ay, v.y);
    }
    if (beg == end) { ax = 0.f; ay = 0.f; }
    float2 o; o.x = ax; o.y = ay;
    *(float2*)&pooled[(size_t)cl * 512 + tid * 2] = o;
}

// ---------------------------------------------------------------------------
// Column-wise sum of squares (axis 0), low-contention (64 blocks)
// ---------------------------------------------------------------------------
__global__ void k_sumsq(const float* __restrict__ pooled, float* __restrict__ sumsq, int NC) {
    int tid = threadIdx.x;  // 256 threads, 2 cols each
    float ax = 0.f, ay = 0.f;
    for (int r = blockIdx.x; r < NC; r += gridDim.x) {
        float2 v = *(const float2*)&pooled[(size_t)r * 512 + tid * 2];
        ax += v.x * v.x; ay += v.y * v.y;
    }
    atomicAdd(&sumsq[tid * 2 + 0], ax);
    atomicAdd(&sumsq[tid * 2 + 1], ay);
}

__global__ void k_scale(const float* __restrict__ pooled, const float* __restrict__ sumsq,
                        float* __restrict__ out, int total) {
    int i = blockIdx.x * blockDim.x + threadIdx.x;
    int base = i * 4;
    if (base < total) {
        float4 v = *(const float4*)&pooled[base];
        int col = base & 511;
        v.x /= (sqrtf(sumsq[col + 0]) + 1e-6f);
        v.y /= (sqrtf(sumsq[col + 1]) + 1e-6f);
        v.z /= (sqrtf(sumsq[col + 2]) + 1e-6f);
        v.w /= (sqrtf(sumsq[col + 3]) + 1e-6f);
        *(float4*)&out[base] = v;
    }
}

// ---------------------------------------------------------------------------
extern "C" void kernel_launch(void* const* d_in, const int* in_sizes, int n_in,
                              void* d_out, int out_size, void* d_ws, size_t ws_size,
                              hipStream_t stream) {
    const float* x0      = (const float*)d_in[0];
    const int*   ei      = (const int*)d_in[1];
    const int*   cluster = (const int*)d_in[2];
    const float* w1_[3] = {(const float*)d_in[3], (const float*)d_in[7],  (const float*)d_in[11]};
    const float* b1_[3] = {(const float*)d_in[4], (const float*)d_in[8],  (const float*)d_in[12]};
    const float* w2_[3] = {(const float*)d_in[5], (const float*)d_in[9],  (const float*)d_in[13]};
    const float* b2_[3] = {(const float*)d_in[6], (const float*)d_in[10], (const float*)d_in[14]};

    const int N  = in_sizes[2];       // 50000
    const int E  = in_sizes[1] / 2;   // 800000
    const int NC = 2500;
    float* out = (float*)d_out;

    char* p = (char*)d_ws;
    auto alloc = [&](size_t bytes) -> char* {
        char* r = p;
        p += (bytes + 255) & ~(size_t)255;
        return r;
    };
    float* x1     = (float*)alloc((size_t)N * 128 * 4);
    float* x2     = (float*)alloc((size_t)N * 256 * 4);
    float* x3     = (float*)alloc((size_t)N * 512 * 4);
    float* tbuf   = (float*)alloc((size_t)N * 64 * 4);
    bfu*   hb0    = (bfu*)alloc((size_t)N * 64 * 2);
    bfu*   hb1    = (bfu*)alloc((size_t)N * 128 * 2);
    bfu*   hb2    = (bfu*)alloc((size_t)N * 256 * 2);
    float* pooled = (float*)alloc((size_t)NC * 512 * 4);
    float* sumsq  = (float*)alloc(512 * 4);
    int*   deg    = (int*)alloc((size_t)(N + 1) * 4);
    int*   rowptr = (int*)alloc((size_t)(N + 1) * 4);
    int*   cursor = (int*)alloc((size_t)(N + 1) * 4);
    int*   colidx = (int*)alloc((size_t)E * 4);
    int*   cdeg   = (int*)alloc((size_t)(NC + 1) * 4);
    int*   cptr   = (int*)alloc((size_t)(NC + 1) * 4);
    int*   ccur   = (int*)alloc((size_t)(NC + 1) * 4);
    int*   cidx   = (int*)alloc((size_t)N * 4);
    int*   scn0   = (int*)alloc((size_t)N * 4);
    int*   scn1   = (int*)alloc((size_t)NC * 4);
    int*   bsum0  = (int*)alloc(256 * 4);
    int*   bsum1  = (int*)alloc(256 * 4);

    const int* src = ei;
    const int* dst = ei + E;

    k_zero3<<<(N + 255) / 256, 256, 0, stream>>>(deg, N, cdeg, NC, sumsq);

    // histograms
    k_hist<<<(E + 255) / 256, 256, 0, stream>>>(dst, E, deg);
    k_hist<<<(N + 255) / 256, 256, 0, stream>>>(cluster, N, cdeg);

    // hierarchical exclusive scan of both segments
    const int nb0 = (N + 255) / 256;
    const int nb1 = (NC + 255) / 256;
    k_scanA<<<dim3(nb0, 2), 256, 0, stream>>>(deg, N, cdeg, NC, scn0, scn1, bsum0, bsum1);
    k_scanB<<<1, 256, 0, stream>>>(bsum0, nb0, bsum1, nb1, rowptr, N, cptr, NC);
    k_scanC<<<dim3(nb0, 2), 256, 0, stream>>>(deg, N, cdeg, NC, scn0, scn1, bsum0, bsum1,
                                              rowptr, cursor, cptr, ccur);

    // scatters
    k_scatter_edges<<<(E + 255) / 256, 256, 0, stream>>>(dst, src, E, cursor, colidx);
    k_scatter_nodes<<<(N + 255) / 256, 256, 0, stream>>>(cluster, N, ccur, cidx);

    const int Mtiles = (N + 63) / 64;
    const int aggBlocks = (N * 64 + 255) / 256;

    // layer 0: c=64
    k_mlp1<64><<<Mtiles, 256, 0, stream>>>(x0, w1_[0], b1_[0], tbuf, N);
    k_mlp2<<<dim3(Mtiles, 1), 256, 0, stream>>>(tbuf, w2_[0], b2_[0], x1, hb0, N, 64, 128);
    k_agg<1><<<aggBlocks, 256, 0, stream>>>(hb0, x1 + 64, rowptr, colidx, N, 128);

    // layer 1: c=128
    k_mlp1<128><<<Mtiles, 256, 0, stream>>>(x1, w1_[1], b1_[1], tbuf, N);
    k_mlp2<<<dim3(Mtiles, 2), 256, 0, stream>>>(tbuf, w2_[1], b2_[1], x2, hb1, N, 128, 256);
    k_agg<2><<<aggBlocks, 256, 0, stream>>>(hb1, x2 + 128, rowptr, colidx, N, 256);

    // layer 2: c=256
    k_mlp1<256><<<Mtiles, 256, 0, stream>>>(x2, w1_[2], b1_[2], tbuf, N);
    k_mlp2<<<dim3(Mtiles, 4), 256, 0, stream>>>(tbuf, w2_[2], b2_[2], x3, hb2, N, 256, 512);
    k_agg<4><<<aggBlocks, 256, 0, stream>>>(hb2, x3 + 256, rowptr, colidx, N, 512);

    // cluster max-pool + column norm
    k_pool<<<NC, 256, 0, stream>>>(x3, cptr, cidx, pooled);
    k_sumsq<<<64, 256, 0, stream>>>(pooled, sumsq, NC);
    k_scale<<<(out_size / 4 + 255) / 256, 256, 0, stream>>>(pooled, sumsq, out, out_size);
}